// Round 1
// baseline (620.450 us; speedup 1.0000x reference)
//
#include <hip/hip_runtime.h>
#include <math.h>

// Problem constants from setup_inputs(): y is (8, 3, 256, 512) fp32, lmbd is (1,3).
#define TVW 512      // row length
#define TVH 256      // H (for channel index)
#define TVC 3        // channels
#define RPB 64       // rows per block == block size (one thread per row)
#define LDS_STRIDE 513  // +1 pad: (i*513 + k) % 32 = (i+k)%32 -> 2 lanes/bank (free)

__global__ __launch_bounds__(64, 1)
void tv1d_condat_kernel(const float* __restrict__ y,
                        const float* __restrict__ lmbd,
                        float* __restrict__ out,
                        int total_rows) {
    extern __shared__ float buf[];   // (64*513 + 4) floats
    const int tid = threadIdx.x;
    const int base_row = blockIdx.x * RPB;
    const int row = base_row + tid;

    // ---- stage 64 contiguous rows (64*512 floats) into LDS with per-row +1 pad ----
    const float* src = y + (size_t)base_row * TVW;
    const int total_f = RPB * TVW;
    for (int f = tid * 4; f < total_f; f += 64 * 4) {
        float4 v = *(const float4*)(src + f);
        int o = f + (f >> 9);            // row j = f>>9; o = j*513 + (f&511)
        buf[o + 0] = v.x; buf[o + 1] = v.y; buf[o + 2] = v.z; buf[o + 3] = v.w;
    }
    __syncthreads();

    if (row < total_rows) {
        const int c = (row / TVH) % TVC;
        const float lam = log1pf(expf(lmbd[c]));   // softplus
        const float nlam = -lam;
        const float twolam = 2.0f * lam;
        float* x = buf + tid * LDS_STRIDE;         // this thread's row, updated in place

        // Condat (2013) Algorithm 1 — identical state machine to the reference.
        int k = 0, k0 = 0, km = 0, kp = 0;
        float vmin = x[0] - lam, vmax = x[0] + lam;
        float umin = lam, umax = nlam;

        // Iteration cap: theoretically unreachable, prevents any hang in the
        // boundary corner the reference also can't reach (jit-safety min()).
        for (int it = 0; it < (1 << 20); ++it) {
            if (k == TVW - 1) {
                if (umin < 0.0f) {              // negative jump at boundary
                    do { x[k0++] = vmin; } while (k0 <= km);
                    int rd = k0 < TVW ? k0 : TVW - 1;
                    k = km = k0;
                    vmin = x[rd];
                    umax = vmin + lam - vmax;
                    umin = lam;
                } else if (umax > 0.0f) {       // positive jump at boundary
                    do { x[k0++] = vmax; } while (k0 <= kp);
                    int rd = k0 < TVW ? k0 : TVW - 1;
                    k = kp = k0;
                    vmax = x[rd];
                    umin = vmax + nlam - vmin;
                    umax = nlam;
                } else {                         // terminate
                    vmin += umin / (float)(k - k0 + 1);
                    do { x[k0++] = vmin; } while (k0 <= k);
                    break;
                }
            } else {
                const float yn = x[k + 1];       // k < W-1, in bounds
                const float umin_t = umin + yn - vmin;
                const float umax_t = umax + yn - vmax;
                if (umin_t < nlam) {             // negative jump: flush at vmin
                    do { x[k0++] = vmin; } while (k0 <= km);
                    k = km = kp = k0;            // k0 = old km+1 <= k < W-1: safe
                    vmin = x[k0];
                    vmax = vmin + twolam;
                    umin = lam; umax = nlam;
                } else if (umax_t > lam) {       // positive jump: flush at vmax
                    do { x[k0++] = vmax; } while (k0 <= kp);
                    k = km = kp = k0;
                    vmax = x[k0];
                    vmin = vmax - twolam;
                    umin = lam; umax = nlam;
                } else {                          // extend current segment
                    ++k;
                    umin = umin_t; umax = umax_t;
                    if (umin >= lam) {
                        vmin += (umin - lam) / (float)(k - k0 + 1);
                        umin = lam; km = k;
                    }
                    if (umax <= nlam) {
                        vmax += (umax + lam) / (float)(k - k0 + 1);
                        umax = nlam; kp = k;
                    }
                }
            }
        }
    }
    __syncthreads();

    // ---- coalesced write-back ----
    float* dst = out + (size_t)base_row * TVW;
    for (int f = tid * 4; f < total_f; f += 64 * 4) {
        int o = f + (f >> 9);
        float4 v;
        v.x = buf[o + 0]; v.y = buf[o + 1]; v.z = buf[o + 2]; v.w = buf[o + 3];
        *(float4*)(dst + f) = v;
    }
}

extern "C" void kernel_launch(void* const* d_in, const int* in_sizes, int n_in,
                              void* d_out, int out_size, void* d_ws, size_t ws_size,
                              hipStream_t stream) {
    const float* y    = (const float*)d_in[0];
    const float* lmbd = (const float*)d_in[1];
    float* out = (float*)d_out;

    const int total_rows = in_sizes[0] / TVW;           // 6144
    const int grid = (total_rows + RPB - 1) / RPB;      // 96 blocks
    const size_t smem = (size_t)(RPB * LDS_STRIDE + 4) * sizeof(float);  // ~131 KB

    // Defensive: allow >64KB dynamic LDS (no-op / harmless on ROCm if not needed).
    (void)hipFuncSetAttribute((const void*)tv1d_condat_kernel,
                              hipFuncAttributeMaxDynamicSharedMemorySize,
                              (int)smem);

    tv1d_condat_kernel<<<grid, RPB, smem, stream>>>(y, lmbd, out, total_rows);
}

// Round 2
// 430.737 us; speedup vs baseline: 1.4404x; 1.4404x over previous
//
#include <hip/hip_runtime.h>
#include <math.h>

// Problem constants from setup_inputs(): y is (8, 3, 256, 512) fp32, lmbd is (1,3).
#define TVW 512      // row length
#define TVH 256      // H (for channel index)
#define TVC 3        // channels
#define WPB 4        // waves per block == rows per block (one wave per row, lanes redundant)
#define BLOCK (WPB * 64)

// One wave per row. All 64 lanes redundantly run the same row's Condat state
// machine -> every branch is wave-uniform (s_cbranch, no exec-mask residue,
// no flush-loop serialization across lanes). LDS holds the original y row
// (read-only; Condat only ever reads original y), so x[k+1] reads are
// same-address broadcasts (zero bank conflicts). Flushed segments go straight
// to global out with the 64 lanes fanned across the segment (coalesced).
__global__ __launch_bounds__(BLOCK)
void tv1d_condat_wave_kernel(const float* __restrict__ y,
                             const float* __restrict__ lmbd,
                             float* __restrict__ out,
                             int total_rows) {
    __shared__ float buf[WPB * TVW];   // 8 KB
    const int tid  = threadIdx.x;
    const int wave = tid >> 6;
    const int lane = tid & 63;
    const int base_row = blockIdx.x * WPB;
    const int row = base_row + wave;

    // ---- stage WPB contiguous rows into LDS, fully coalesced float4 ----
    {
        float4* b4 = (float4*)buf;
        const float4* s4 = (const float4*)(y + (size_t)base_row * TVW);
        #pragma unroll
        for (int i = 0; i < (WPB * TVW / 4); i += BLOCK)
            b4[i + tid] = s4[i + tid];
    }
    __syncthreads();

    if (row < total_rows) {
        const int c = (row / TVH) % TVC;
        const float lam    = log1pf(expf(lmbd[c]));  // softplus
        const float nlam   = -lam;
        const float twolam = 2.0f * lam;
        const float* x = buf + wave * TVW;           // read-only original y
        float* o = out + (size_t)row * TVW;

        // Condat (2013) Algorithm 1 — same state machine as the reference.
        int k = 0, k0 = 0, km = 0, kp = 0;
        float vmin = x[0] - lam, vmax = x[0] + lam;
        float umin = lam, umax = nlam;

        // Iteration cap: theoretically unreachable; prevents any hang in the
        // boundary corner the reference also guards with min().
        for (int it = 0; it < (1 << 20); ++it) {
            if (k == TVW - 1) {
                if (umin < 0.0f) {               // negative jump at boundary
                    for (int p = k0 + lane; p <= km; p += 64) o[p] = vmin;
                    k0 = km + 1;
                    const int rd = k0 < TVW ? k0 : TVW - 1;
                    k = km = k0;
                    vmin = x[rd];
                    umax = vmin + lam - vmax;
                    umin = lam;
                } else if (umax > 0.0f) {        // positive jump at boundary
                    for (int p = k0 + lane; p <= kp; p += 64) o[p] = vmax;
                    k0 = kp + 1;
                    const int rd = k0 < TVW ? k0 : TVW - 1;
                    k = kp = k0;
                    vmax = x[rd];
                    umin = vmax + nlam - vmin;
                    umax = nlam;
                } else {                          // terminate: flush tail
                    const float v = vmin + umin / (float)(k - k0 + 1);
                    for (int p = k0 + lane; p <= k; p += 64) o[p] = v;
                    break;
                }
            } else {
                const float yn = x[k + 1];        // broadcast LDS read
                const float umin_t = umin + yn - vmin;
                const float umax_t = umax + yn - vmax;
                if (umin_t < nlam) {              // negative jump: flush at vmin
                    for (int p = k0 + lane; p <= km; p += 64) o[p] = vmin;
                    k0 = km + 1;                  // km <= TVW-2 here -> k0 <= TVW-1
                    k = km = kp = k0;
                    vmin = x[k0];
                    vmax = vmin + twolam;
                    umin = lam; umax = nlam;
                } else if (umax_t > lam) {        // positive jump: flush at vmax
                    for (int p = k0 + lane; p <= kp; p += 64) o[p] = vmax;
                    k0 = kp + 1;
                    k = km = kp = k0;
                    vmax = x[k0];
                    vmin = vmax - twolam;
                    umin = lam; umax = nlam;
                } else {                           // extend current segment
                    ++k;
                    umin = umin_t; umax = umax_t;
                    if (umin >= lam) {
                        vmin += (umin - lam) / (float)(k - k0 + 1);
                        umin = lam; km = k;
                    }
                    if (umax <= nlam) {
                        vmax += (umax + lam) / (float)(k - k0 + 1);
                        umax = nlam; kp = k;
                    }
                }
            }
        }
    }
}

extern "C" void kernel_launch(void* const* d_in, const int* in_sizes, int n_in,
                              void* d_out, int out_size, void* d_ws, size_t ws_size,
                              hipStream_t stream) {
    const float* y    = (const float*)d_in[0];
    const float* lmbd = (const float*)d_in[1];
    float* out = (float*)d_out;

    const int total_rows = in_sizes[0] / TVW;              // 6144
    const int grid = (total_rows + WPB - 1) / WPB;         // 1536 blocks
    tv1d_condat_wave_kernel<<<grid, BLOCK, 0, stream>>>(y, lmbd, out, total_rows);
}

// Round 3
// 379.988 us; speedup vs baseline: 1.6328x; 1.1336x over previous
//
#include <hip/hip_runtime.h>
#include <math.h>

// Problem constants: y is (8, 3, 256, 512) fp32, lmbd is (1,3).
#define TVW 512      // row length
#define TVH 256      // H (for channel index)
#define TVC 3        // channels
#define WPB 2        // waves (= rows) per block; block=128 -> 16 blk/CU * 2 = 32 waves/CU cap
#define BLOCK (WPB * 64)

// One wave per row; all 64 lanes redundantly run the same row's Condat state
// machine (wave-uniform branches, broadcast LDS reads). Output is built
// IN PLACE in the LDS row (flushed prefix [..k0) is never re-read), so flush
// stores are cheap ds_writes; one coalesced float4 writeback at the end.
// Divisions replaced by v_rcp_f32; denominator maintained incrementally as
// float; extend-path hit updates are branchless (min/max/fma + cndmask).
__global__ __launch_bounds__(BLOCK)
void tv1d_condat_wave_kernel(const float* __restrict__ y,
                             const float* __restrict__ lmbd,
                             float* __restrict__ out,
                             int total_rows) {
    __shared__ float buf[WPB * TVW];   // 4 KB
    const int tid  = threadIdx.x;
    const int wave = tid >> 6;
    const int lane = tid & 63;
    const int base_row = blockIdx.x * WPB;
    const int row = base_row + wave;

    // ---- stage WPB contiguous rows into LDS, coalesced float4 ----
    {
        float4* b4 = (float4*)buf;
        const float4* s4 = (const float4*)(y + (size_t)base_row * TVW);
        #pragma unroll
        for (int i = 0; i < (WPB * TVW / 4); i += BLOCK)
            b4[i + tid] = s4[i + tid];
    }
    __syncthreads();

    if (row < total_rows) {
        const int c = (row / TVH) % TVC;
        const float lam    = log1pf(expf(lmbd[c]));  // softplus
        const float nlam   = -lam;
        const float twolam = 2.0f * lam;
        float* x = buf + wave * TVW;   // in-place: read frontier >= k0, writes < k0

        // Condat (2013) Algorithm 1 — same state machine as the reference.
        int k = 0, k0 = 0, km = 0, kp = 0;
        float vmin = x[0] - lam, vmax = x[0] + lam;
        float umin = lam, umax = nlam;
        float denf = 1.0f;             // (k - k0 + 1) as float, maintained incrementally
        float yn = x[1];               // x[k+1] for the loop top (W >= 2)

        for (int it = 0; it < (1 << 20); ++it) {
            if (k == TVW - 1) {
                if (umin < 0.0f) {                 // negative jump at boundary
                    for (int p = k0 + lane; p <= km; p += 64) x[p] = vmin;
                    k0 = km + 1;
                    const int rd = k0 < TVW ? k0 : TVW - 1;
                    k = km = k0;
                    vmin = x[rd];                  // kp, vmax unchanged (per reference)
                    umax = vmin + lam - vmax;
                    umin = lam;
                    denf = 1.0f;
                    yn = x[rd + 1 < TVW ? rd + 1 : TVW - 1];
                } else if (umax > 0.0f) {          // positive jump at boundary
                    for (int p = k0 + lane; p <= kp; p += 64) x[p] = vmax;
                    k0 = kp + 1;
                    const int rd = k0 < TVW ? k0 : TVW - 1;
                    k = kp = k0;
                    vmax = x[rd];                  // km, vmin unchanged (per reference)
                    umin = vmax + nlam - vmin;
                    umax = nlam;
                    denf = 1.0f;
                    yn = x[rd + 1 < TVW ? rd + 1 : TVW - 1];
                } else {                           // terminate: flush tail
                    const float v = vmin + umin * __builtin_amdgcn_rcpf(denf);
                    for (int p = k0 + lane; p <= k; p += 64) x[p] = v;
                    break;
                }
            } else {
                // yn == x[k+1]; prefetch x[k+2] (dead on flush paths)
                const float ypre = x[k + 2 < TVW ? k + 2 : TVW - 1];
                const float umin_t = umin + yn - vmin;
                const float umax_t = umax + yn - vmax;
                if (umin_t < nlam) {               // negative jump: flush at vmin
                    for (int p = k0 + lane; p <= km; p += 64) x[p] = vmin;
                    k0 = km + 1;                   // km <= k <= W-2 -> k0 <= W-1
                    k = km = kp = k0;
                    vmin = x[k0];
                    vmax = vmin + twolam;
                    umin = lam; umax = nlam;
                    denf = 1.0f;
                    yn = x[k0 + 1 < TVW ? k0 + 1 : TVW - 1];
                } else if (umax_t > lam) {         // positive jump: flush at vmax
                    for (int p = k0 + lane; p <= kp; p += 64) x[p] = vmax;
                    k0 = kp + 1;
                    k = km = kp = k0;
                    vmax = x[k0];
                    vmin = vmax - twolam;
                    umin = lam; umax = nlam;
                    denf = 1.0f;
                    yn = x[k0 + 1 < TVW ? k0 + 1 : TVW - 1];
                } else {                           // extend (branchless hit updates)
                    ++k;
                    denf += 1.0f;
                    const float r = __builtin_amdgcn_rcpf(denf);
                    const bool hm = umin_t >= lam;
                    const bool hp = umax_t <= nlam;
                    // not-hit => fmaxf/fminf clamps the delta to 0 => v unchanged
                    vmin = fmaf(fmaxf(umin_t - lam, 0.0f), r, vmin);
                    vmax = fmaf(fminf(umax_t + lam, 0.0f), r, vmax);
                    umin = fminf(umin_t, lam);
                    umax = fmaxf(umax_t, nlam);
                    km = hm ? k : km;
                    kp = hp ? k : kp;
                    yn = ypre;
                }
            }
        }
    }
    __syncthreads();

    // ---- coalesced float4 writeback LDS -> out ----
    {
        float4* b4 = (float4*)buf;
        float4* d4 = (float4*)(out + (size_t)base_row * TVW);
        #pragma unroll
        for (int i = 0; i < (WPB * TVW / 4); i += BLOCK)
            d4[i + tid] = b4[i + tid];
    }
}

extern "C" void kernel_launch(void* const* d_in, const int* in_sizes, int n_in,
                              void* d_out, int out_size, void* d_ws, size_t ws_size,
                              hipStream_t stream) {
    const float* y    = (const float*)d_in[0];
    const float* lmbd = (const float*)d_in[1];
    float* out = (float*)d_out;

    const int total_rows = in_sizes[0] / TVW;              // 6144
    const int grid = (total_rows + WPB - 1) / WPB;         // 3072 blocks
    tv1d_condat_wave_kernel<<<grid, BLOCK, 0, stream>>>(y, lmbd, out, total_rows);
}

// Round 4
// 300.063 us; speedup vs baseline: 2.0677x; 1.2664x over previous
//
#include <hip/hip_runtime.h>
#include <math.h>

// Problem constants: y is (8, 3, 256, 512) fp32, lmbd is (1,3).
#define TVW 512      // row length
#define TVH 256      // H (for channel index)
#define TVC 3        // channels
#define WPB 2        // waves (= rows) per block; 3072 blocks -> 12 blk/CU, 24 waves/CU
#define BLOCK (WPB * 64)

// One wave per row; all 64 lanes redundantly run the same row's Condat state
// machine. Restructured for wave-uniform control flow:
//  - inner loop = extend-only, trip count uniform (readfirstlane) -> SALU loop
//  - single rare exit via __ballot -> scalar branch, no exec-mask churn
//  - v_rcp replaced by LDS reciprocal table (uniform index -> broadcast)
//  - yn and r prefetched one iteration ahead; +4-float pad kills clamps
// Output built in place in the LDS row; one coalesced float4 writeback.
__global__ __launch_bounds__(BLOCK)
void tv1d_condat_wave_kernel(const float* __restrict__ y,
                             const float* __restrict__ lmbd,
                             float* __restrict__ out,
                             int total_rows) {
    __shared__ __align__(16) float buf[WPB * TVW + 4];
    __shared__ float rtab[520];        // rtab[i] = 1/i (i>=1)
    const int tid  = threadIdx.x;
    const int wave = tid >> 6;
    const int lane = tid & 63;
    const int base_row = blockIdx.x * WPB;
    const int row = base_row + wave;

    // ---- stage WPB contiguous rows into LDS (coalesced float4) + recip table ----
    {
        float4* b4 = (float4*)buf;
        const float4* s4 = (const float4*)(y + (size_t)base_row * TVW);
        #pragma unroll
        for (int i = 0; i < (WPB * TVW / 4); i += BLOCK)
            b4[i + tid] = s4[i + tid];
    }
    for (int i = tid; i < 520; i += BLOCK)
        rtab[i] = 1.0f / (float)(i == 0 ? 1 : i);
    __syncthreads();

    if (row < total_rows) {
        const int c = (row / TVH) % TVC;
        float lam = log1pf(expf(lmbd[c]));   // softplus, once per row
        lam = __uint_as_float(__builtin_amdgcn_readfirstlane(__float_as_uint(lam)));
        const float nlam   = -lam;
        const float twolam = 2.0f * lam;
        float* x = buf + wave * TVW;         // in place; prefix [..k0) never re-read

        // Condat (2013) Algorithm 1 state. Inner loop always entered with k==k0.
        int k0 = 0, km = 0, kp = 0;
        float vmin = x[0] - lam, vmax = x[0] + lam;
        float umin = lam, umax = nlam;

        for (int guard = 0; guard < 4096; ++guard) {
            int trips_v = (TVW - 1) - k0;
            if (trips_v < 0) trips_v = 0;
            const int trips = __builtin_amdgcn_readfirstlane(trips_v);

            float yn = x[k0 + 1];            // pad-safe even if k0 == W-1
            float rn = rtab[2];
            const float* xpp = x + (k0 + 2);
            const float* rpp = rtab + 3;
            const int kb = k0 + 1;           // k after extend at trip t: kb + t

            float umin_t = 0.0f, umax_t = 0.0f;
            int t = 0;
            for (; t < trips; ++t) {
                const float yn2 = xpp[t];    // x[k0+2+t], pad-safe
                const float rn2 = rpp[t];    // rtab[3+t] = 1/(t+3)
                umin_t = umin + yn - vmin;
                umax_t = umax + yn - vmax;
                const bool jump = (umin_t < nlam) | (umax_t > lam);
                if (__ballot(jump)) break;   // scalar branch (mask uniform)
                const int kc = kb + t;
                km = (umin_t >= lam)  ? kc : km;
                kp = (umax_t <= nlam) ? kc : kp;
                vmin = fmaf(fmaxf(umin_t - lam, 0.0f), rn, vmin);  // rn = 1/(t+2)
                vmax = fmaf(fminf(umax_t + lam, 0.0f), rn, vmax);
                umin = fminf(umin_t, lam);
                umax = fmaxf(umax_t, nlam);
                yn = yn2; rn = rn2;
            }

            if (t < trips) {
                // ---- mid-row jump at transition k=k0+t -> k+1 ----
                if (umin_t < nlam) {         // negative jump: flush [k0..km] at vmin
                    const int pe = km < TVW - 1 ? km : TVW - 1;
                    for (int p = k0 + lane; p <= pe; p += 64) x[p] = vmin;
                    k0 = km + 1;             // km <= W-2 here
                    km = kp = k0;
                    vmin = x[k0];
                    vmax = vmin + twolam;
                } else {                     // positive jump: flush [k0..kp] at vmax
                    const int pe = kp < TVW - 1 ? kp : TVW - 1;
                    for (int p = k0 + lane; p <= pe; p += 64) x[p] = vmax;
                    k0 = kp + 1;
                    km = kp = k0;
                    vmax = x[k0];
                    vmin = vmax - twolam;
                }
                umin = lam; umax = nlam;
            } else {
                // ---- boundary: k == W-1, den = trips+1 ----
                if (umin < 0.0f) {           // flush [k0..km] at vmin; keep kp,vmax
                    const int pe = km < TVW - 1 ? km : TVW - 1;
                    for (int p = k0 + lane; p <= pe; p += 64) x[p] = vmin;
                    k0 = km + 1;
                    km = k0;
                    vmin = x[k0 < TVW ? k0 : TVW - 1];
                    umax = vmin + lam - vmax;
                    umin = lam;
                } else if (umax > 0.0f) {    // flush [k0..kp] at vmax; keep km,vmin
                    const int pe = kp < TVW - 1 ? kp : TVW - 1;
                    for (int p = k0 + lane; p <= pe; p += 64) x[p] = vmax;
                    k0 = kp + 1;
                    kp = k0;
                    vmax = x[k0 < TVW ? k0 : TVW - 1];
                    umin = vmax + nlam - vmin;
                    umax = nlam;
                } else {                     // terminate: flush tail at mean value
                    const float v = vmin + umin * rtab[trips + 1];
                    for (int p = k0 + lane; p < TVW; p += 64) x[p] = v;
                    break;
                }
            }
        }
    }
    __syncthreads();

    // ---- coalesced float4 writeback LDS -> out ----
    {
        float4* b4 = (float4*)buf;
        float4* d4 = (float4*)(out + (size_t)base_row * TVW);
        #pragma unroll
        for (int i = 0; i < (WPB * TVW / 4); i += BLOCK)
            d4[i + tid] = b4[i + tid];
    }
}

extern "C" void kernel_launch(void* const* d_in, const int* in_sizes, int n_in,
                              void* d_out, int out_size, void* d_ws, size_t ws_size,
                              hipStream_t stream) {
    const float* y    = (const float*)d_in[0];
    const float* lmbd = (const float*)d_in[1];
    float* out = (float*)d_out;

    const int total_rows = in_sizes[0] / TVW;              // 6144
    const int grid = (total_rows + WPB - 1) / WPB;         // 3072 blocks
    tv1d_condat_wave_kernel<<<grid, BLOCK, 0, stream>>>(y, lmbd, out, total_rows);
}